// Round 1
// baseline (86.881 us; speedup 1.0000x reference)
//
#include <hip/hip_runtime.h>
#include <hip/hip_bf16.h>
#include <cstdint>

// DLM breadth-2 forward. B=16, n=128, C=64.
// out = [out0 (16*64) | out1 (16*128*64) | out2 (16*128*128*64)], fp32.
//
// out2[b,i,j,c] = sigmoid( PA[b,i,c] + PB[b,j,c]
//                          + x2[b,i,j,:]·W2[64:128,c] + x2[b,j,i,:]·W2[192:256,c] )
// with PA = x1·W2[0:64] + b2, PB = x1·W2[128:192]  (precomputed).
// The x2 part is a per-(b,i) GEMM [128j x 128k]·[128k x 64c] done in bf16 MFMA.

#define NDIM 128
#define CDIM 64

typedef float f32x4 __attribute__((ext_vector_type(4)));
typedef short s16x8 __attribute__((ext_vector_type(8)));

__device__ __forceinline__ unsigned short f2bf(float f) {
    union { float f; unsigned int u; } v; v.f = f;
    unsigned int u = v.u;
    return (unsigned short)((u + 0x7FFFu + ((u >> 16) & 1u)) >> 16);  // RNE
}
__device__ __forceinline__ float sigmoidf_(float x) {
    return 1.0f / (1.0f + __expf(-x));
}

// ---- prep: PA[b,i,c] = b2[c] + sum_k x1[b,i,k] W2[k][c]
//            PB[b,i,c] =         sum_k x1[b,i,k] W2[128+k][c]
__global__ void prep_pab(const float* __restrict__ x1, const float* __restrict__ W2,
                         const float* __restrict__ b2,
                         float* __restrict__ PA, float* __restrict__ PB) {
    int blk = blockIdx.x;          // b*128 + i
    int c = threadIdx.x;           // 0..63
    __shared__ float xv[64];
    xv[c] = x1[blk * 64 + c];
    __syncthreads();
    float accA = b2[c];
    float accB = 0.f;
#pragma unroll 8
    for (int k = 0; k < 64; ++k) {
        float xk = xv[k];
        accA += xk * W2[k * 64 + c];
        accB += xk * W2[(128 + k) * 64 + c];
    }
    PA[blk * 64 + c] = accA;
    PB[blk * 64 + c] = accB;
}

// ---- prep: WT[n][k] bf16, n<64, k<128. k<64 -> W2[64+k][n]; k>=64 -> W2[128+k][n]
__global__ void prep_wt(const float* __restrict__ W2, unsigned short* __restrict__ WT) {
    int idx = blockIdx.x * 256 + threadIdx.x;   // 0..8191
    int n = idx >> 7, k = idx & 127;
    int row = (k < 64) ? (64 + k) : (128 + k);
    WT[idx] = f2bf(W2[row * 64 + n]);
}

// ---- out0: [16,64]
__global__ void k_out0(const float* __restrict__ x0, const float* __restrict__ x1,
                       const float* __restrict__ W0, const float* __restrict__ b0,
                       float* __restrict__ out0) {
    int b = blockIdx.x, c = threadIdx.x;   // 64 threads
    __shared__ float f0[136];
    float mx = -1e30f, mn = 1e30f;
    for (int j = 0; j < 128; ++j) {
        float v = x1[(b * 128 + j) * 64 + c];
        mx = fmaxf(mx, v); mn = fminf(mn, v);
    }
    f0[8 + c] = mx;
    f0[72 + c] = mn;
    if (c < 8) f0[c] = x0[b * 8 + c];
    __syncthreads();
    float acc = b0[c];
    for (int k = 0; k < 136; ++k) acc += f0[k] * W0[k * 64 + c];
    out0[b * 64 + c] = sigmoidf_(acc);
}

// ---- out1: [16,128,64]; exclude-self max/min over j of x2[b,i,:,:] + matvec W1
__global__ __launch_bounds__(256) void k_out1(const float* __restrict__ x0,
        const float* __restrict__ x1, const float* __restrict__ x2,
        const float* __restrict__ W1, const float* __restrict__ b1,
        float* __restrict__ out1) {
    int blk = blockIdx.x;          // b*128 + i
    int b = blk >> 7, i = blk & 127;
    int t = threadIdx.x;
    int c = t & 63, g = t >> 6;
    const float* base = x2 + (size_t)blk * (NDIM * CDIM);
    float mx = 0.0f, mn = 1.0f;    // reference fills diag with 0 (max) / 1 (min)
#pragma unroll 4
    for (int jj = 0; jj < 32; ++jj) {
        int j = g * 32 + jj;
        float v = base[j * 64 + c];
        if (j != i) { mx = fmaxf(mx, v); mn = fminf(mn, v); }
    }
    __shared__ float sf[200];
    __shared__ float smax[4][64], smin[4][64], spart[4][64];
    smax[g][c] = mx; smin[g][c] = mn;
    __syncthreads();
    if (t < 64) {
        float M = fmaxf(fmaxf(smax[0][c], smax[1][c]), fmaxf(smax[2][c], smax[3][c]));
        float m = fminf(fminf(smin[0][c], smin[1][c]), fminf(smin[2][c], smin[3][c]));
        sf[72 + c] = M; sf[136 + c] = m;
        sf[8 + c] = x1[blk * 64 + c];
        if (c < 8) sf[c] = x0[b * 8 + c];
    }
    __syncthreads();
    {
        int k0 = g * 50;
        float acc = 0.f;
#pragma unroll 10
        for (int k = k0; k < k0 + 50; ++k) acc += sf[k] * W1[k * 64 + c];
        spart[g][c] = acc;
    }
    __syncthreads();
    if (t < 64) {
        float acc = spart[0][c] + spart[1][c] + spart[2][c] + spart[3][c] + b1[c];
        out1[blk * 64 + c] = sigmoidf_(acc);
    }
}

// ---- out2 main GEMM: one block per (b,i). 4 waves; M=128(j) N=64(c) K=128.
__global__ __launch_bounds__(256) void k_out2(const float* __restrict__ x2,
        const unsigned short* __restrict__ WT, const float* __restrict__ PA,
        const float* __restrict__ PB, float* __restrict__ out2) {
    int blk = blockIdx.x;          // b*128 + i
    int b = blk >> 7, i = blk & 127;
    int t = threadIdx.x;
    int lane = t & 63, w = t >> 6;

    __shared__ __align__(16) unsigned short Ald[128 * 128];  // 32KB bf16, XOR-swizzled
    __shared__ float pai[64];

    // stage xa: A[j][k], k=0..63  <- x2[b,i,j,c]  (contiguous 32KB)
    const float* xaSrc = x2 + (size_t)blk * (NDIM * CDIM);
#pragma unroll
    for (int p = 0; p < 8; ++p) {
        int f4 = p * 256 + t;              // float4 index 0..2047
        int e = f4 * 4;
        int j = e >> 6, cc = e & 63;
        float4 v = *reinterpret_cast<const float4*>(xaSrc + e);
        ushort4 u;
        u.x = f2bf(v.x); u.y = f2bf(v.y); u.z = f2bf(v.z); u.w = f2bf(v.w);
        // ushort index: j*128 + (k ^ ((j&7)<<3))
        *reinterpret_cast<ushort4*>(&Ald[j * 128 + (cc ^ ((j & 7) << 3))]) = u;
    }
    // stage xb: A[j][64+k] <- x2[b,j,i,c]  (128 strided rows of 256B)
#pragma unroll
    for (int p = 0; p < 8; ++p) {
        int j = p * 16 + (t >> 4);
        int cc = (t & 15) * 4;
        const float* src = x2 + (size_t)(((b * 128 + j) * 128 + i)) * 64 + cc;
        float4 v = *reinterpret_cast<const float4*>(src);
        ushort4 u;
        u.x = f2bf(v.x); u.y = f2bf(v.y); u.z = f2bf(v.z); u.w = f2bf(v.w);
        *reinterpret_cast<ushort4*>(&Ald[j * 128 + ((64 + cc) ^ ((j & 7) << 3))]) = u;
    }
    if (t < 64) pai[t] = PA[blk * 64 + t];

    // B fragments in registers: bfrag[ks][nt], lane: n = nt*16+(lane&15), k = ks*32+(lane>>4)*8
    s16x8 bfrag[4][4];
#pragma unroll
    for (int ks = 0; ks < 4; ++ks)
#pragma unroll
        for (int nt = 0; nt < 4; ++nt) {
            int n = nt * 16 + (lane & 15);
            int k0 = ks * 32 + (lane >> 4) * 8;
            bfrag[ks][nt] = *reinterpret_cast<const s16x8*>(WT + n * 128 + k0);
        }

    f32x4 acc[2][4];
#pragma unroll
    for (int m = 0; m < 2; ++m)
#pragma unroll
        for (int nt = 0; nt < 4; ++nt) acc[m][nt] = (f32x4){0.f, 0.f, 0.f, 0.f};

    __syncthreads();

#pragma unroll
    for (int ks = 0; ks < 4; ++ks) {
#pragma unroll
        for (int m = 0; m < 2; ++m) {
            int row = (w * 2 + m) * 16 + (lane & 15);
            int u8 = (ks * 4 + (lane >> 4)) * 8;           // ushort offset of 16B chunk
            s16x8 afrag = *reinterpret_cast<const s16x8*>(
                &Ald[row * 128 + (u8 ^ ((row & 7) << 3))]);
#pragma unroll
            for (int nt = 0; nt < 4; ++nt)
                acc[m][nt] = __builtin_amdgcn_mfma_f32_16x16x32_bf16(
                    afrag, bfrag[ks][nt], acc[m][nt], 0, 0, 0);
        }
    }

    // epilogue: D row=(lane>>4)*4+r (j within tile), col=lane&15 (c within tile)
    const float* PBb = PB + b * 128 * 64;
    float* outBase = out2 + (size_t)blk * (NDIM * CDIM);
#pragma unroll
    for (int m = 0; m < 2; ++m) {
        int jt = (w * 2 + m) * 16 + (lane >> 4) * 4;
#pragma unroll
        for (int nt = 0; nt < 4; ++nt) {
            int cp = nt * 16 + (lane & 15);
            float pav = pai[cp];
#pragma unroll
            for (int r = 0; r < 4; ++r) {
                int j = jt + r;
                float val = acc[m][nt][r] + pav + PBb[j * 64 + cp];
                outBase[j * 64 + cp] = sigmoidf_(val);
            }
        }
    }
}

extern "C" void kernel_launch(void* const* d_in, const int* in_sizes, int n_in,
                              void* d_out, int out_size, void* d_ws, size_t ws_size,
                              hipStream_t stream) {
    const float* x0 = (const float*)d_in[0];
    const float* x1 = (const float*)d_in[1];
    const float* x2 = (const float*)d_in[2];
    const float* W0 = (const float*)d_in[3];
    const float* b0 = (const float*)d_in[4];
    const float* W1 = (const float*)d_in[5];
    const float* b1 = (const float*)d_in[6];
    const float* W2 = (const float*)d_in[7];
    const float* b2 = (const float*)d_in[8];

    float* out0 = (float*)d_out;
    float* out1 = out0 + 16 * 64;
    float* out2 = out1 + 16 * 128 * 64;

    float* PA = (float*)d_ws;                    // 16*128*64 f32
    float* PB = PA + 16 * 128 * 64;              // 16*128*64 f32
    unsigned short* WT = (unsigned short*)(PB + 16 * 128 * 64);  // 64*128 bf16

    prep_pab<<<16 * 128, 64, 0, stream>>>(x1, W2, b2, PA, PB);
    prep_wt<<<32, 256, 0, stream>>>(W2, WT);
    k_out0<<<16, 64, 0, stream>>>(x0, x1, W0, b0, out0);
    k_out1<<<16 * 128, 256, 0, stream>>>(x0, x1, x2, W1, b1, out1);
    k_out2<<<16 * 128, 256, 0, stream>>>(x2, WT, PA, PB, out2);
}

// Round 2
// 60.620 us; speedup vs baseline: 1.4332x; 1.4332x over previous
//
#include <hip/hip_runtime.h>
#include <hip/hip_bf16.h>
#include <cstdint>

// DLM breadth-2 forward. B=16, n=128, C=64.
// out = [out0 (16*64) | out1 (16*128*64) | out2 (16*128*128*64)], fp32.
//
// out2[b,i,j,c] = sigmoid( PA[b,i,c] + PB[b,j,c]
//                          + x2[b,i,j,:]·W2[64:128,c] + x2[b,j,i,:]·W2[192:256,c] )
// with PA = x1·W2[0:64] + b2, PB = x1·W2[128:192]  (precomputed).
// out1 is fused into the out2 kernel (reuses the fp32 x2 row-slab loads).

#define NDIM 128
#define CDIM 64

typedef float f32x4 __attribute__((ext_vector_type(4)));
typedef short s16x8 __attribute__((ext_vector_type(8)));

__device__ __forceinline__ unsigned short f2bf(float f) {
    union { float f; unsigned int u; } v; v.f = f;
    unsigned int u = v.u;
    return (unsigned short)((u + 0x7FFFu + ((u >> 16) & 1u)) >> 16);  // RNE
}
__device__ __forceinline__ float sigmoidf_(float x) {
    return 1.0f / (1.0f + __expf(-x));
}

// ---- prep: PA[b,i,c] = b2[c] + sum_k x1[b,i,k] W2[k][c]
//            PB[b,i,c] =         sum_k x1[b,i,k] W2[128+k][c]
__global__ void prep_pab(const float* __restrict__ x1, const float* __restrict__ W2,
                         const float* __restrict__ b2,
                         float* __restrict__ PA, float* __restrict__ PB) {
    int blk = blockIdx.x;          // b*128 + i
    int c = threadIdx.x;           // 0..63
    __shared__ float xv[64];
    xv[c] = x1[blk * 64 + c];
    __syncthreads();
    float accA = b2[c];
    float accB = 0.f;
#pragma unroll 8
    for (int k = 0; k < 64; ++k) {
        float xk = xv[k];
        accA += xk * W2[k * 64 + c];
        accB += xk * W2[(128 + k) * 64 + c];
    }
    PA[blk * 64 + c] = accA;
    PB[blk * 64 + c] = accB;
}

// ---- prep: WT[n][k] bf16, n<64, k<128. k<64 -> W2[64+k][n]; k>=64 -> W2[128+k][n]
__global__ void prep_wt(const float* __restrict__ W2, unsigned short* __restrict__ WT) {
    int idx = blockIdx.x * 256 + threadIdx.x;   // 0..8191
    int n = idx >> 7, k = idx & 127;
    int row = (k < 64) ? (64 + k) : (128 + k);
    WT[idx] = f2bf(W2[row * 64 + n]);
}

// ---- out0: [16,64]  (256 threads: float4 loads + shuffle reduce)
__global__ __launch_bounds__(256) void k_out0(const float* __restrict__ x0,
        const float* __restrict__ x1, const float* __restrict__ W0,
        const float* __restrict__ b0, float* __restrict__ out0) {
    int b = blockIdx.x;
    int t = threadIdx.x;
    int lane = t & 63, w = t >> 6;
    int q = lane & 15;             // c-quad
    int jq = lane >> 4;            // 0..3
    __shared__ float pw[4][64], pn[4][64], f0[136], spart[4][64];

    f32x4 mx = {-1e30f, -1e30f, -1e30f, -1e30f};
    f32x4 mn = {1e30f, 1e30f, 1e30f, 1e30f};
#pragma unroll
    for (int p = 0; p < 8; ++p) {
        int j = (w * 4 + jq) + 16 * p;
        float4 v = *reinterpret_cast<const float4*>(x1 + ((size_t)(b * 128 + j)) * 64 + q * 4);
        mx.x = fmaxf(mx.x, v.x); mx.y = fmaxf(mx.y, v.y);
        mx.z = fmaxf(mx.z, v.z); mx.w = fmaxf(mx.w, v.w);
        mn.x = fminf(mn.x, v.x); mn.y = fminf(mn.y, v.y);
        mn.z = fminf(mn.z, v.z); mn.w = fminf(mn.w, v.w);
    }
#pragma unroll
    for (int d = 16; d <= 32; d <<= 1) {
        mx.x = fmaxf(mx.x, __shfl_xor(mx.x, d)); mx.y = fmaxf(mx.y, __shfl_xor(mx.y, d));
        mx.z = fmaxf(mx.z, __shfl_xor(mx.z, d)); mx.w = fmaxf(mx.w, __shfl_xor(mx.w, d));
        mn.x = fminf(mn.x, __shfl_xor(mn.x, d)); mn.y = fminf(mn.y, __shfl_xor(mn.y, d));
        mn.z = fminf(mn.z, __shfl_xor(mn.z, d)); mn.w = fminf(mn.w, __shfl_xor(mn.w, d));
    }
    if (lane < 16) {
        *reinterpret_cast<f32x4*>(&pw[w][lane * 4]) = mx;
        *reinterpret_cast<f32x4*>(&pn[w][lane * 4]) = mn;
    }
    __syncthreads();
    if (t < 64) {
        int c = t;
        float M = fmaxf(fmaxf(pw[0][c], pw[1][c]), fmaxf(pw[2][c], pw[3][c]));
        float m = fminf(fminf(pn[0][c], pn[1][c]), fminf(pn[2][c], pn[3][c]));
        f0[8 + c] = M; f0[72 + c] = m;
        if (c < 8) f0[c] = x0[b * 8 + c];
    }
    __syncthreads();
    {
        int g = t >> 6, c = t & 63;
        float acc = 0.f;
#pragma unroll
        for (int k = g * 34; k < g * 34 + 34; ++k) acc += f0[k] * W0[k * 64 + c];
        spart[g][c] = acc;
    }
    __syncthreads();
    if (t < 64) {
        int c = t;
        out0[b * 64 + c] = sigmoidf_(spart[0][c] + spart[1][c] + spart[2][c] + spart[3][c] + b0[c]);
    }
}

// ---- fused out1+out2: one block per (b,i). 4 waves, each wave owns j-rows
// [32w, 32w+32): stages its own A rows (barrier-free GEMM), computes fp32
// exclude-self max/min partials from the same loads, then the out1 matvec tail.
__global__ __launch_bounds__(256) void k_fused(const float* __restrict__ x0,
        const float* __restrict__ x1, const float* __restrict__ x2,
        const unsigned short* __restrict__ WT,
        const float* __restrict__ W1, const float* __restrict__ b1,
        const float* __restrict__ PA, const float* __restrict__ PB,
        float* __restrict__ out1, float* __restrict__ out2) {
    int blk = blockIdx.x;          // b*128 + i
    int b = blk >> 7, i = blk & 127;
    int t = threadIdx.x;
    int lane = t & 63, w = t >> 6;
    int jq = lane >> 4;            // 0..3
    int cc = (lane & 15) * 4;      // c-quad base

    __shared__ __align__(16) unsigned short Ald[128 * 128];  // 32KB bf16, XOR-swizzled
    __shared__ float pwmax[4][64], pwmin[4][64], spart[4][64], sf[200];

    const float* xaSrc = x2 + (size_t)blk * (NDIM * CDIM);

    // ---- phase 1: xa rows (x2[b,i,j,:]) -> regs, max/min partials, LDS
    float4 va[8];
#pragma unroll
    for (int p = 0; p < 8; ++p) {
        int j = 32 * w + p * 4 + jq;
        va[p] = *reinterpret_cast<const float4*>(xaSrc + j * 64 + cc);
    }
    f32x4 mx = {0.f, 0.f, 0.f, 0.f}, mn = {1.f, 1.f, 1.f, 1.f};  // diag fill values
#pragma unroll
    for (int p = 0; p < 8; ++p) {
        int j = 32 * w + p * 4 + jq;
        bool ok = (j != i);
        float ax = ok ? va[p].x : 0.0f, ay = ok ? va[p].y : 0.0f;
        float az = ok ? va[p].z : 0.0f, aw = ok ? va[p].w : 0.0f;
        mx.x = fmaxf(mx.x, ax); mx.y = fmaxf(mx.y, ay);
        mx.z = fmaxf(mx.z, az); mx.w = fmaxf(mx.w, aw);
        float ix = ok ? va[p].x : 1.0f, iy = ok ? va[p].y : 1.0f;
        float iz = ok ? va[p].z : 1.0f, iw = ok ? va[p].w : 1.0f;
        mn.x = fminf(mn.x, ix); mn.y = fminf(mn.y, iy);
        mn.z = fminf(mn.z, iz); mn.w = fminf(mn.w, iw);
        ushort4 u;
        u.x = f2bf(va[p].x); u.y = f2bf(va[p].y); u.z = f2bf(va[p].z); u.w = f2bf(va[p].w);
        *reinterpret_cast<ushort4*>(&Ald[j * 128 + (cc ^ ((j & 7) << 3))]) = u;
    }
    // wave-reduce partials across the 4 jq groups (lanes l, l^16, l^32)
#pragma unroll
    for (int d = 16; d <= 32; d <<= 1) {
        mx.x = fmaxf(mx.x, __shfl_xor(mx.x, d)); mx.y = fmaxf(mx.y, __shfl_xor(mx.y, d));
        mx.z = fmaxf(mx.z, __shfl_xor(mx.z, d)); mx.w = fmaxf(mx.w, __shfl_xor(mx.w, d));
        mn.x = fminf(mn.x, __shfl_xor(mn.x, d)); mn.y = fminf(mn.y, __shfl_xor(mn.y, d));
        mn.z = fminf(mn.z, __shfl_xor(mn.z, d)); mn.w = fminf(mn.w, __shfl_xor(mn.w, d));
    }
    if (lane < 16) {
        *reinterpret_cast<f32x4*>(&pwmax[w][lane * 4]) = mx;
        *reinterpret_cast<f32x4*>(&pwmin[w][lane * 4]) = mn;
    }

    // ---- phase 2: xb rows (x2[b,j,i,:]) -> LDS (k = 64..127)
#pragma unroll
    for (int p = 0; p < 8; ++p) {
        int j = 32 * w + p * 4 + jq;
        float4 v = *reinterpret_cast<const float4*>(
            x2 + ((size_t)((b * 128 + j) * 128 + i)) * 64 + cc);
        ushort4 u;
        u.x = f2bf(v.x); u.y = f2bf(v.y); u.z = f2bf(v.z); u.w = f2bf(v.w);
        *reinterpret_cast<ushort4*>(&Ald[j * 128 + ((64 + cc) ^ ((j & 7) << 3))]) = u;
    }

    // ---- B fragments from WT (L2-hot): n = nt*16+(lane&15), k = ks*32+(lane>>4)*8
    s16x8 bfrag[4][4];
#pragma unroll
    for (int ks = 0; ks < 4; ++ks)
#pragma unroll
        for (int nt = 0; nt < 4; ++nt) {
            int n = nt * 16 + (lane & 15);
            int k0 = ks * 32 + (lane >> 4) * 8;
            bfrag[ks][nt] = *reinterpret_cast<const s16x8*>(WT + n * 128 + k0);
        }

    f32x4 acc[2][4];
#pragma unroll
    for (int m = 0; m < 2; ++m)
#pragma unroll
        for (int nt = 0; nt < 4; ++nt) acc[m][nt] = (f32x4){0.f, 0.f, 0.f, 0.f};

    // wave-local: our ds_writes are the only producer of the rows we read.
    // LDS ops per wave complete in order; fence the compiler, not the block.
    asm volatile("s_waitcnt lgkmcnt(0)" ::: "memory");
    __builtin_amdgcn_sched_barrier(0);

    // ---- MFMA over own rows [32w, 32w+32)
#pragma unroll
    for (int ks = 0; ks < 4; ++ks) {
#pragma unroll
        for (int m = 0; m < 2; ++m) {
            int row = 32 * w + m * 16 + (lane & 15);
            int u8 = (ks * 4 + (lane >> 4)) * 8;   // ushort offset of 16B chunk
            s16x8 afrag = *reinterpret_cast<const s16x8*>(
                &Ald[row * 128 + (u8 ^ ((row & 7) << 3))]);
#pragma unroll
            for (int nt = 0; nt < 4; ++nt)
                acc[m][nt] = __builtin_amdgcn_mfma_f32_16x16x32_bf16(
                    afrag, bfrag[ks][nt], acc[m][nt], 0, 0, 0);
        }
    }

    // ---- out2 epilogue: D row=(lane>>4)*4+r (j), col=lane&15 (c)
    const float* PBb = PB + b * 128 * 64;
    const float* PAi = PA + blk * 64;
    float* outBase = out2 + (size_t)blk * (NDIM * CDIM);
#pragma unroll
    for (int m = 0; m < 2; ++m) {
        int jt = 32 * w + m * 16 + (lane >> 4) * 4;
#pragma unroll
        for (int nt = 0; nt < 4; ++nt) {
            int cp = nt * 16 + (lane & 15);
            float pav = PAi[cp];
#pragma unroll
            for (int r = 0; r < 4; ++r) {
                int j = jt + r;
                outBase[j * 64 + cp] = sigmoidf_(acc[m][nt][r] + pav + PBb[j * 64 + cp]);
            }
        }
    }

    // ---- out1 tail (needs all waves' partials)
    __syncthreads();
    int c = t & 63;
    if (t < 64) {
        float M = fmaxf(fmaxf(pwmax[0][c], pwmax[1][c]), fmaxf(pwmax[2][c], pwmax[3][c]));
        float m2 = fminf(fminf(pwmin[0][c], pwmin[1][c]), fminf(pwmin[2][c], pwmin[3][c]));
        sf[72 + c] = M; sf[136 + c] = m2;
        sf[8 + c] = x1[blk * 64 + c];
        if (c < 8) sf[c] = x0[b * 8 + c];
    }
    __syncthreads();
    {
        int g = t >> 6;
        float acc1 = 0.f;
#pragma unroll 10
        for (int k = g * 50; k < g * 50 + 50; ++k) acc1 += sf[k] * W1[k * 64 + c];
        spart[g][c] = acc1;
    }
    __syncthreads();
    if (t < 64) {
        out1[blk * 64 + c] = sigmoidf_(
            spart[0][c] + spart[1][c] + spart[2][c] + spart[3][c] + b1[c]);
    }
}

extern "C" void kernel_launch(void* const* d_in, const int* in_sizes, int n_in,
                              void* d_out, int out_size, void* d_ws, size_t ws_size,
                              hipStream_t stream) {
    const float* x0 = (const float*)d_in[0];
    const float* x1 = (const float*)d_in[1];
    const float* x2 = (const float*)d_in[2];
    const float* W0 = (const float*)d_in[3];
    const float* b0 = (const float*)d_in[4];
    const float* W1 = (const float*)d_in[5];
    const float* b1 = (const float*)d_in[6];
    const float* W2 = (const float*)d_in[7];
    const float* b2 = (const float*)d_in[8];

    float* out0 = (float*)d_out;
    float* out1 = out0 + 16 * 64;
    float* out2 = out1 + 16 * 128 * 64;

    float* PA = (float*)d_ws;                    // 16*128*64 f32
    float* PB = PA + 16 * 128 * 64;              // 16*128*64 f32
    unsigned short* WT = (unsigned short*)(PB + 16 * 128 * 64);  // 64*128 bf16

    prep_pab<<<16 * 128, 64, 0, stream>>>(x1, W2, b2, PA, PB);
    prep_wt<<<32, 256, 0, stream>>>(W2, WT);
    k_out0<<<16, 256, 0, stream>>>(x0, x1, W0, b0, out0);
    k_fused<<<16 * 128, 256, 0, stream>>>(x0, x1, x2, WT, W1, b1, PA, PB, out1, out2);
}